// Round 12
// baseline (883.599 us; speedup 1.0000x reference)
//
#include <hip/hip_runtime.h>
#include <hip/hip_bf16.h>

// DimeNet-like GNN, f32 in/out. Round 11: MEASUREMENT ROUND. Same structure
// as round 10 (412 us best), but the four per-layer kernels take a runtime
// `reps` argument and re-execute their compute+store section `reps` times
// (idempotent: plain stores; h ping-pongs between two buffers so node_f
// never reads its own output). Host passes reps=8 so each dispatch runs 8x
// its true duration and finally surfaces in the rocprof top-5 with real
// counters. (dur - 412)/7 = true 3-layer kernel sum.

#define N_NODES 16000
#define N_EDGES 256000
#define N_TRI   640000
#define N_B     128
#define OUT_DIM 32
#define L_LAYERS 3

typedef __hip_bfloat16 bf16;
typedef short s8v __attribute__((ext_vector_type(8)));
typedef float f4v __attribute__((ext_vector_type(4)));

__device__ __forceinline__ float ldx(const void* p, size_t i, int f) {
    if (f) return ((const float*)p)[i];
    return __bfloat162float(((const bf16*)p)[i]);
}

__device__ __forceinline__ unsigned short f2bf_rne(float x) {
    unsigned int u = __float_as_uint(x);
    unsigned int r = (u + 0x7FFFu + ((u >> 16) & 1u)) >> 16;
    return (unsigned short)r;
}
__device__ __forceinline__ float bf2f(unsigned short b) {
    return __uint_as_float(((unsigned int)b) << 16);
}
__device__ __forceinline__ void split2(float a, unsigned short& h, unsigned short& l) {
    h = f2bf_rne(a);
    l = f2bf_rne(a - bf2f(h));
}
__device__ __forceinline__ void make_afrag(const float* av, s8v& ah, s8v& al) {
    #pragma unroll
    for (int j = 0; j < 8; j++) {
        unsigned short h, l; split2(av[j], h, l);
        ah[j] = (short)h; al[j] = (short)l;
    }
}

__device__ __forceinline__ void stageW(const void* W, size_t offW, int KS, int f,
                                       unsigned short* sBhi, unsigned short* sBlo) {
    for (int idx = threadIdx.x; idx < KS * 2048; idx += 256) {
        int jj = idx & 7, ln = (idx >> 3) & 63, nt = (idx >> 9) & 3, ks = idx >> 11;
        int k = ks * 32 + (ln >> 4) * 8 + jj;
        int n = nt * 16 + (ln & 15);
        float w = ldx(W, offW + (size_t)k * 64 + n, f);
        unsigned short h_, l_; split2(w, h_, l_);
        sBhi[idx] = h_; sBlo[idx] = l_;
    }
}

__device__ __forceinline__ void mfma3(const unsigned short* sBhi, const unsigned short* sBlo,
                                      int ks, int lane, const s8v& ah, const s8v& al,
                                      f4v acc[4]) {
    #pragma unroll
    for (int nt = 0; nt < 4; nt++) {
        s8v bh = *(const s8v*)&sBhi[(ks * 4 + nt) * 512 + lane * 8];
        s8v bl = *(const s8v*)&sBlo[(ks * 4 + nt) * 512 + lane * 8];
        acc[nt] = __builtin_amdgcn_mfma_f32_16x16x32_bf16(ah, bh, acc[nt], 0, 0, 0);
        acc[nt] = __builtin_amdgcn_mfma_f32_16x16x32_bf16(al, bh, acc[nt], 0, 0, 0);
        acc[nt] = __builtin_amdgcn_mfma_f32_16x16x32_bf16(ah, bl, acc[nt], 0, 0, 0);
    }
}

__device__ __forceinline__ void ldrow8(const void* A, int fa, size_t row, int ks,
                                       int quad, float av[8]) {
    if (fa) {
        const float* p = (const float*)A + row * 64 + ks * 32 + quad * 8;
        float4 x0 = ((const float4*)p)[0], x1 = ((const float4*)p)[1];
        av[0] = x0.x; av[1] = x0.y; av[2] = x0.z; av[3] = x0.w;
        av[4] = x1.x; av[5] = x1.y; av[6] = x1.z; av[7] = x1.w;
    } else {
        const bf16* p = (const bf16*)A + row * 64 + ks * 32 + quad * 8;
        #pragma unroll
        for (int j = 0; j < 8; j++) av[j] = __bfloat162float(p[j]);
    }
}

// ---------------------------------------------------------------- diag helpers
__global__ void k_probe(const void* __restrict__ rbf, int* __restrict__ flag) {
    if (threadIdx.x == 0 && blockIdx.x == 0) {
        const float* p = (const float*)rbf;
        int good = 0;
        for (int i = 0; i < 256; i++) {
            float v = fabsf(p[i]);
            if (v > 1e-4f && v < 100.0f) good++;
        }
        *flag = (good > 192) ? 1 : 0;
    }
}
__global__ void k_fill(void* __restrict__ out, const int* __restrict__ flag,
                       float val, int n) {
    int i = blockIdx.x * blockDim.x + threadIdx.x;
    if (i < n) {
        if (*flag) ((float*)out)[i] = val;
        else       ((bf16*)out)[i] = __float2bfloat16(val);
    }
}

// ---------------------------------------------------------------- setup
__global__ void k_setup(const void* __restrict__ rbf, int* __restrict__ flag,
                        int* __restrict__ cur) {
    int i = blockIdx.x * blockDim.x + threadIdx.x;
    int stride = gridDim.x * blockDim.x;
    for (; i < 2 * N_NODES; i += stride) cur[i] = 0;
    if (blockIdx.x == 0 && threadIdx.x == 0) {
        const float* p = (const float*)rbf;
        int good = 0;
        for (int q = 0; q < 256; q++) {
            float v = fabsf(p[q]);
            if (v > 1e-4f && v < 100.0f) good++;
        }
        *flag = (good > 192) ? 1 : 0;
    }
}

__global__ void k_hist2(const int* __restrict__ j_idx, const int* __restrict__ edge_index,
                        int* __restrict__ cur_t, int* __restrict__ cur_e) {
    const int TB = (N_TRI + 255) / 256;
    if ((int)blockIdx.x < TB) {
        int i = blockIdx.x * 256 + threadIdx.x;
        if (i < N_TRI) {
            unsigned j = (unsigned)j_idx[i];
            if (j < N_NODES) atomicAdd(&cur_t[j], 1);
        }
    } else {
        int i = (blockIdx.x - TB) * 256 + threadIdx.x;
        if (i < N_EDGES) {
            unsigned d = (unsigned)edge_index[N_EDGES + i];
            if (d < N_NODES) atomicAdd(&cur_e[d], 1);
        }
    }
}

__global__ __launch_bounds__(256) void k_scan2(int* __restrict__ a, int* __restrict__ b) {
    int* cnt = (blockIdx.x == 0) ? a : b;
    __shared__ int part[256];
    int tid = threadIdx.x;
    const int PER = (N_NODES + 255) / 256;
    int base = tid * PER;
    int s = 0;
    for (int i = 0; i < PER; i++) {
        int idx = base + i;
        if (idx < N_NODES) s += cnt[idx];
    }
    part[tid] = s;
    __syncthreads();
    for (int d = 1; d < 256; d <<= 1) {
        int v = (tid >= d) ? part[tid - d] : 0;
        __syncthreads();
        part[tid] += v;
        __syncthreads();
    }
    int run = (tid > 0) ? part[tid - 1] : 0;
    for (int i = 0; i < PER; i++) {
        int idx = base + i;
        if (idx < N_NODES) {
            int v = cnt[idx];
            cnt[idx] = run;
            run += v;
        }
    }
}

__global__ void k_scatter2(const int* __restrict__ j_idx, const int* __restrict__ k_idx,
                           const int* __restrict__ edge_index,
                           int* __restrict__ cur_t, int* __restrict__ cur_e,
                           int* __restrict__ tri_o, int* __restrict__ k_srt,
                           int* __restrict__ src_s) {
    const int TB = (N_TRI + 255) / 256;
    if ((int)blockIdx.x < TB) {
        int i = blockIdx.x * 256 + threadIdx.x;
        if (i < N_TRI) {
            unsigned j = (unsigned)j_idx[i];
            if (j < N_NODES) {
                int pos = atomicAdd(&cur_t[j], 1);
                if ((unsigned)pos < (unsigned)N_TRI) {
                    unsigned k = (unsigned)k_idx[i]; if (k >= N_NODES) k = 0;
                    tri_o[pos] = i;
                    k_srt[pos] = (int)k;
                }
            }
        }
    } else {
        int e = (blockIdx.x - TB) * 256 + threadIdx.x;
        if (e < N_EDGES) {
            unsigned d = (unsigned)edge_index[N_EDGES + e];
            if (d < N_NODES) {
                int pos = atomicAdd(&cur_e[d], 1);
                if ((unsigned)pos < (unsigned)N_EDGES) {
                    unsigned s = (unsigned)edge_index[e]; if (s >= N_NODES) s = 0;
                    src_s[pos] = (int)s;
                }
            }
        }
    }
}

// ---------------------------------------------------------------- lin2out (reps)
__global__ __launch_bounds__(256) void k_lin2out(
    const void* __restrict__ A1, int a1ws,
    const void* __restrict__ W1, size_t offW1, const void* __restrict__ b1,
    const void* __restrict__ W2, size_t offW2, const void* __restrict__ b2,
    size_t offB, const int* __restrict__ flag, int reps,
    float* __restrict__ X, float* __restrict__ Y) {
    __shared__ unsigned short h1[2 * 2048], l1[2 * 2048];
    __shared__ unsigned short h2[2 * 2048], l2[2 * 2048];
    __shared__ float sB1[64], sB2[64];
    int f = *flag;
    int fa = a1ws ? 1 : f;
    stageW(W1, offW1, 2, f, h1, l1);
    stageW(W2, offW2, 2, f, h2, l2);
    if (threadIdx.x < 64) {
        sB1[threadIdx.x] = ldx(b1, offB + threadIdx.x, f);
        sB2[threadIdx.x] = ldx(b2, offB + threadIdx.x, f);
    }
    __syncthreads();
    int lane = threadIdx.x & 63;
    int quad = lane >> 4;
    int m = lane & 15;
    int tile = blockIdx.x * 4 + (threadIdx.x >> 6);
    size_t row = (size_t)tile * 16 + m;
    for (int rep = 0; rep < reps; rep++) {
        f4v accH[4], accS[4];
        #pragma unroll
        for (int nt = 0; nt < 4; nt++) {
            float bh = sB1[nt * 16 + m], bs = sB2[nt * 16 + m];
            accH[nt] = (f4v){bh, bh, bh, bh};
            accS[nt] = (f4v){bs, bs, bs, bs};
        }
        float av[8]; s8v ah, al;
        #pragma unroll
        for (int ks = 0; ks < 2; ks++) {
            ldrow8(A1, fa, row, ks, quad, av);
            make_afrag(av, ah, al);
            mfma3(h1, l1, ks, lane, ah, al, accH);
            mfma3(h2, l2, ks, lane, ah, al, accS);
        }
        #pragma unroll
        for (int r = 0; r < 4; r++) {
            size_t rr = (size_t)(tile * 16 + quad * 4 + r) * 64 + m;
            #pragma unroll
            for (int nt = 0; nt < 4; nt++) {
                X[rr + nt * 16] = accH[nt][r];
                Y[rr + nt * 16] = accS[nt][r];
            }
        }
    }
}

// ---------------------------------------------------------------- tri segment sum (reps)
__global__ __launch_bounds__(256) void k_tri_seg(
    const int* __restrict__ ends, const int* __restrict__ tri_o,
    const int* __restrict__ k_srt, const float* __restrict__ Hh,
    const void* __restrict__ rbf, const void* __restrict__ cbf,
    const void* __restrict__ W1, size_t offW,
    const int* __restrict__ flag, int reps, float* __restrict__ agg_e) {
    int f = *flag;
    int c = threadIdx.x & 63;
    float wr[6], wc[6];
    #pragma unroll
    for (int q = 0; q < 6; q++) {
        wr[q] = ldx(W1, offW + (size_t)(64 + q) * 64 + c, f);
        wc[q] = ldx(W1, offW + (size_t)(70 + q) * 64 + c, f);
    }
    int j = blockIdx.x * 4 + (threadIdx.x >> 6);
    int p0 = (j == 0) ? 0 : ends[j - 1];
    int p1 = ends[j];
    if (p0 < 0) p0 = 0; if (p0 > N_TRI) p0 = N_TRI;
    if (p1 < p0) p1 = p0; if (p1 > N_TRI) p1 = N_TRI;
    float rb = 0.f;
    #pragma unroll
    for (int q = 0; q < 6; q++)
        rb += ldx(rbf, (size_t)j * 6 + q, f) * wr[q];
    for (int rep = 0; rep < reps; rep++) {
        float s = 0.f;
        for (int p = p0; p < p1; p += 4) {
            int tq[4], kq[4];
            float hv[4], cb[4][6];
            #pragma unroll
            for (int i = 0; i < 4; i++) {
                int ok = (p + i < p1);
                int t = ok ? tri_o[p + i] : -1;
                if ((unsigned)t >= N_TRI) t = -1;
                tq[i] = t;
                int k = ok ? k_srt[p + i] : 0;
                if ((unsigned)k >= N_NODES) k = 0;
                kq[i] = k;
            }
            #pragma unroll
            for (int i = 0; i < 4; i++)
                hv[i] = Hh[(size_t)kq[i] * 64 + c];
            #pragma unroll
            for (int i = 0; i < 4; i++) {
                if (tq[i] >= 0) {
                    if (f) {
                        const float2* cp = (const float2*)((const float*)cbf + (size_t)tq[i] * 6);
                        float2 c0 = cp[0], c1 = cp[1], c2 = cp[2];
                        cb[i][0] = c0.x; cb[i][1] = c0.y; cb[i][2] = c1.x;
                        cb[i][3] = c1.y; cb[i][4] = c2.x; cb[i][5] = c2.y;
                    } else {
                        #pragma unroll
                        for (int q = 0; q < 6; q++)
                            cb[i][q] = ldx(cbf, (size_t)tq[i] * 6 + q, 0);
                    }
                }
            }
            #pragma unroll
            for (int i = 0; i < 4; i++) {
                if (tq[i] < 0) continue;
                float v = hv[i] + rb;
                #pragma unroll
                for (int q = 0; q < 6; q++)
                    v += cb[i][q] * wc[q];
                s += fmaxf(v, 0.f);
            }
        }
        agg_e[(size_t)j * 64 + c] = s;
    }
}

// ---------------------------------------------------------------- edge segment sum (reps)
__global__ __launch_bounds__(256) void k_edge_f(
    const int* __restrict__ ends, const int* __restrict__ src_s,
    const float* __restrict__ Hs, const float* __restrict__ agg_e,
    const void* __restrict__ W2, size_t offW2a, const int* __restrict__ flag,
    int reps, float* __restrict__ aggr) {
    __shared__ float sW[64 * 64];
    int f = *flag;
    for (int idx = threadIdx.x; idx < 4096; idx += 256)
        sW[idx] = ldx(W2, offW2a + idx, f);
    __syncthreads();
    int c = threadIdx.x & 63;
    int d = blockIdx.x * 4 + (threadIdx.x >> 6);
    int p0 = (d == 0) ? 0 : ends[d - 1];
    int p1 = ends[d];
    if (p0 < 0) p0 = 0; if (p0 > N_EDGES) p0 = N_EDGES;
    if (p1 < p0) p1 = p0; if (p1 > N_EDGES) p1 = N_EDGES;
    for (int rep = 0; rep < reps; rep++) {
        float av = agg_e[(size_t)d * 64 + c];
        float ad = 0.f;
        #pragma unroll
        for (int k = 0; k < 64; k++)
            ad += __shfl(av, k) * sW[k * 64 + c];
        float s = 0.f;
        for (int p = p0; p < p1; p += 8) {
            int ss[8];
            float hv[8];
            #pragma unroll
            for (int i = 0; i < 8; i++) {
                int sv = (p + i < p1) ? src_s[p + i] : 0;
                if ((unsigned)sv >= N_NODES) sv = 0;
                ss[i] = sv;
            }
            #pragma unroll
            for (int i = 0; i < 8; i++)
                hv[i] = Hs[(size_t)ss[i] * 64 + c];
            #pragma unroll
            for (int i = 0; i < 8; i++)
                if (p + i < p1) s += fmaxf(hv[i] + ad, 0.f);
        }
        aggr[(size_t)d * 64 + c] = s;
    }
}

// ---------------------------------------------------------------- node MLP (reps; out != in)
__global__ __launch_bounds__(256) void k_node_f(
    const void* __restrict__ A1, int a1ws, const float* __restrict__ aggr,
    const void* __restrict__ Wn1, const void* __restrict__ bn1,
    const void* __restrict__ Wn2, const void* __restrict__ bn2,
    size_t offW1, size_t offB, size_t offW2,
    const int* __restrict__ flag, int reps, float* __restrict__ hout) {
    __shared__ unsigned short s1h[4 * 2048], s1l[4 * 2048];
    __shared__ unsigned short s2h[2 * 2048], s2l[2 * 2048];
    __shared__ float sB1[64], sB2[64];
    __shared__ float zbuf[4][16 * 68];
    int f = *flag;
    int fa = a1ws ? 1 : f;
    stageW(Wn1, offW1, 4, f, s1h, s1l);
    stageW(Wn2, offW2, 2, f, s2h, s2l);
    if (threadIdx.x < 64) {
        sB1[threadIdx.x] = ldx(bn1, offB + threadIdx.x, f);
        sB2[threadIdx.x] = ldx(bn2, offB + threadIdx.x, f);
    }
    __syncthreads();
    int lane = threadIdx.x & 63;
    int quad = lane >> 4;
    int m = lane & 15;
    int w = threadIdx.x >> 6;
    int tile = blockIdx.x * 4 + w;
    size_t row = (size_t)tile * 16 + m;
    for (int rep = 0; rep < reps; rep++) {
        f4v acc[4];
        #pragma unroll
        for (int nt = 0; nt < 4; nt++) {
            float b = sB1[nt * 16 + m];
            acc[nt] = (f4v){b, b, b, b};
        }
        float av[8]; s8v ah, al;
        #pragma unroll
        for (int ks = 0; ks < 2; ks++) {
            ldrow8(A1, fa, row, ks, quad, av);
            make_afrag(av, ah, al);
            mfma3(s1h, s1l, ks, lane, ah, al, acc);
        }
        #pragma unroll
        for (int ks = 0; ks < 2; ks++) {
            ldrow8(aggr, 1, row, ks, quad, av);
            make_afrag(av, ah, al);
            mfma3(s1h, s1l, 2 + ks, lane, ah, al, acc);
        }
        #pragma unroll
        for (int r = 0; r < 4; r++)
            #pragma unroll
            for (int nt = 0; nt < 4; nt++)
                zbuf[w][(quad * 4 + r) * 68 + nt * 16 + m] = fmaxf(acc[nt][r], 0.f);
        f4v acc2[4];
        #pragma unroll
        for (int nt = 0; nt < 4; nt++) {
            float b = sB2[nt * 16 + m];
            acc2[nt] = (f4v){b, b, b, b};
        }
        #pragma unroll
        for (int ks = 0; ks < 2; ks++) {
            #pragma unroll
            for (int jx = 0; jx < 8; jx++)
                av[jx] = zbuf[w][m * 68 + ks * 32 + quad * 8 + jx];
            make_afrag(av, ah, al);
            mfma3(s2h, s2l, ks, lane, ah, al, acc2);
        }
        #pragma unroll
        for (int r = 0; r < 4; r++) {
            size_t rr = (size_t)(tile * 16 + quad * 4 + r) * 64 + m;
            #pragma unroll
            for (int nt = 0; nt < 4; nt++)
                hout[rr + nt * 16] = acc2[nt][r];
        }
    }
}

// ---------------------------------------------------------------- pool + head
__global__ __launch_bounds__(256) void k_poolhead(
    const float* __restrict__ h, const int* __restrict__ batch,
    const void* __restrict__ Wo1, const void* __restrict__ bo1,
    const void* __restrict__ Wo2, const void* __restrict__ bo2,
    const int* __restrict__ flag, void* __restrict__ out) {
    __shared__ float red[4][64];
    int b = blockIdx.x;
    int lo = 0, hi = N_NODES;
    while (lo < hi) { int mid = (lo + hi) >> 1; if (batch[mid] < b) lo = mid + 1; else hi = mid; }
    int start = lo;
    hi = N_NODES;
    while (lo < hi) { int mid = (lo + hi) >> 1; if (batch[mid] < b + 1) lo = mid + 1; else hi = mid; }
    int end = lo;
    int lane = threadIdx.x & 63;
    int w = threadIdx.x >> 6;
    float s = 0.f;
    for (int n = start + w; n < end; n += 4)
        s += h[(size_t)n * 64 + lane];
    red[w][lane] = s;
    __syncthreads();
    if (w == 0) {
        int f = *flag;
        float tot = red[0][lane] + red[1][lane] + red[2][lane] + red[3][lane];
        float c = (float)(end - start);
        float p = fmaxf(tot / fmaxf(c, 1.0f), 0.f);
        float acc = ldx(bo1, lane, f);
        #pragma unroll
        for (int kk = 0; kk < 64; kk++)
            acc += __shfl(p, kk) * ldx(Wo1, kk * 64 + lane, f);
        float t1 = fmaxf(acc, 0.f);
        float acc2 = (lane < OUT_DIM) ? ldx(bo2, lane, f) : 0.f;
        #pragma unroll
        for (int kk = 0; kk < 64; kk++) {
            float wv = (lane < OUT_DIM) ? ldx(Wo2, kk * OUT_DIM + lane, f) : 0.f;
            acc2 += __shfl(t1, kk) * wv;
        }
        if (lane < OUT_DIM) {
            if (f) ((float*)out)[b * OUT_DIM + lane] = acc2;
            else   ((bf16*)out)[b * OUT_DIM + lane] = __float2bfloat16(acc2);
        }
    }
}

extern "C" void kernel_launch(void* const* d_in, const int* in_sizes, int n_in,
                              void* d_out, int out_size, void* d_ws, size_t ws_size,
                              hipStream_t stream) {
    const int expect[19] = {
        N_NODES * 64, N_EDGES * 6, N_TRI * 6,
        L_LAYERS * 76 * 64, L_LAYERS * 64,
        L_LAYERS * 128 * 64, L_LAYERS * 64,
        L_LAYERS * 128 * 64, L_LAYERS * 64,
        L_LAYERS * 64 * 64, L_LAYERS * 64,
        64 * 64, 64, 64 * OUT_DIM, OUT_DIM,
        2 * N_EDGES, N_TRI, N_TRI, N_NODES
    };

    char* ws = (char*)d_ws;
    float* hA     = (float*)(ws + 0);            // 4,096,000
    float* agg_e  = (float*)(ws + 4096000);      // 4,096,000
    float* aggr   = (float*)(ws + 8192000);      // 4,096,000
    float* X      = (float*)(ws + 12288000);     // 4,096,000 (Hh)
    float* Y      = (float*)(ws + 16384000);     // 4,096,000 (Hs)
    int*   flag   = (int*)(ws + 20480000);       // 256
    int*   cur_t  = (int*)(ws + 20480256);       // 64,000
    int*   cur_e  = (int*)(ws + 20544256);       // 64,000
    int*   tri_o  = (int*)(ws + 20608256);       // 2,560,000
    int*   k_srt  = (int*)(ws + 23168256);       // 2,560,000
    int*   src_s  = (int*)(ws + 25728256);       // 1,024,000
    float* hB     = (float*)(ws + 26752256);     // 4,096,000
    const size_t FULL_NEED = 30848256u;

    const int out_n = N_B * OUT_DIM;
    const int REPS = 8;  // measurement round: x8 internal replication

    int perm[19];
    bool used[64];
    for (int i = 0; i < 64; i++) used[i] = false;
    int fail_slot = -1;
    for (int i = 0; i < 19; i++) {
        perm[i] = -1;
        for (int jj = 0; jj < n_in && jj < 64; jj++) {
            if (!used[jj] && in_sizes[jj] == expect[i]) { used[jj] = true; perm[i] = jj; break; }
        }
        if (perm[i] < 0 && fail_slot < 0) fail_slot = i;
    }

    if (n_in < 19 || fail_slot >= 0 || ws_size < FULL_NEED) {
        float code = (ws_size < FULL_NEED) ? 40000.0f
                   : (n_in < 19)           ? 50000.0f
                   : 20000.0f + 1000.0f * (float)fail_slot;
        k_probe<<<1, 64, 0, stream>>>(d_in[0], (int*)d_ws);
        k_fill<<<(out_n + 255) / 256, 256, 0, stream>>>(d_out, (int*)d_ws, code, out_n);
        return;
    }

    const void* x    = d_in[perm[0]];
    const void* rbf  = d_in[perm[1]];
    const void* cbf  = d_in[perm[2]];
    const void* W1   = d_in[perm[3]];
    const void* b1   = d_in[perm[4]];
    const void* W2   = d_in[perm[5]];
    const void* b2   = d_in[perm[6]];
    const void* Wn1  = d_in[perm[7]];
    const void* bn1  = d_in[perm[8]];
    const void* Wn2  = d_in[perm[9]];
    const void* bn2  = d_in[perm[10]];
    const void* Wo1  = d_in[perm[11]];
    const void* bo1  = d_in[perm[12]];
    const void* Wo2  = d_in[perm[13]];
    const void* bo2  = d_in[perm[14]];
    const int* edge_index = (const int*)d_in[perm[15]];
    const int* k_idx = (const int*)d_in[perm[16]];
    const int* j_idx = (const int*)d_in[perm[17]];
    const int* batch = (const int*)d_in[perm[18]];

    const int TB = (N_TRI + 255) / 256;
    const int EB = (N_EDGES + 255) / 256;

    k_setup<<<64, 256, 0, stream>>>(rbf, flag, cur_t);
    k_hist2<<<TB + EB, 256, 0, stream>>>(j_idx, edge_index, cur_t, cur_e);
    k_scan2<<<2, 256, 0, stream>>>(cur_t, cur_e);
    k_scatter2<<<TB + EB, 256, 0, stream>>>(j_idx, k_idx, edge_index,
                                            cur_t, cur_e, tri_o, k_srt, src_s);

    // ping-pong h: l0: x->hA, l1: hA->hB, l2: hB->hA; poolhead reads hA
    const void* hc = x;
    int hws = 0;
    float* hout = hA;
    for (int l = 0; l < L_LAYERS; l++) {
        size_t offW1l = (size_t)l * 76 * 64;
        size_t offW2l = (size_t)l * 128 * 64;
        size_t offWn2 = (size_t)l * 64 * 64;
        size_t offB   = (size_t)l * 64;
        k_lin2out<<<250, 256, 0, stream>>>(hc, hws, W1, offW1l, b1,
                                           W2, offW2l, b2, offB, flag, REPS, X, Y);
        k_tri_seg<<<4000, 256, 0, stream>>>(cur_t, tri_o, k_srt, X, rbf, cbf,
                                            W1, offW1l, flag, REPS, agg_e);
        k_edge_f<<<4000, 256, 0, stream>>>(cur_e, src_s, Y, agg_e,
                                           W2, offW2l + 64 * 64, flag, REPS, aggr);
        k_node_f<<<250, 256, 0, stream>>>(hc, hws, aggr, Wn1, bn1, Wn2, bn2,
                                          offW2l, offB, offWn2, flag, REPS, hout);
        hc = hout; hws = 1;
        hout = (hout == hA) ? hB : hA;
    }
    k_poolhead<<<N_B, 256, 0, stream>>>(hA, batch, Wo1, bo1, Wo2, bo2, flag, d_out);
}

// Round 13
// 388.568 us; speedup vs baseline: 2.2740x; 2.2740x over previous
//
#include <hip/hip_runtime.h>
#include <hip/hip_bf16.h>

// DimeNet-like GNN, f32 in/out. Round 12 (from round-11 measurement):
// k_edge_f's fused Ad shfl-GEMV was a 64-step serial dependent chain
// (~15us/layer, 59 of the 67us total warm kernel time). Un-fused into a
// dedicated MFMA pass (k_lin1: Ad = agg_e @ W2a -> reuses X buffer); edge
// kernel now does one coalesced Ad load per bucket. All intermediate
// buffers stored with __builtin_nontemporal_store to evict dirty lines
// from the producer XCD's L2 (cross-XCD first-touch cost).

#define N_NODES 16000
#define N_EDGES 256000
#define N_TRI   640000
#define N_B     128
#define OUT_DIM 32
#define L_LAYERS 3

typedef __hip_bfloat16 bf16;
typedef short s8v __attribute__((ext_vector_type(8)));
typedef float f4v __attribute__((ext_vector_type(4)));

#define NTS(p, v) __builtin_nontemporal_store((v), (p))

__device__ __forceinline__ float ldx(const void* p, size_t i, int f) {
    if (f) return ((const float*)p)[i];
    return __bfloat162float(((const bf16*)p)[i]);
}

__device__ __forceinline__ unsigned short f2bf_rne(float x) {
    unsigned int u = __float_as_uint(x);
    unsigned int r = (u + 0x7FFFu + ((u >> 16) & 1u)) >> 16;
    return (unsigned short)r;
}
__device__ __forceinline__ float bf2f(unsigned short b) {
    return __uint_as_float(((unsigned int)b) << 16);
}
__device__ __forceinline__ void split2(float a, unsigned short& h, unsigned short& l) {
    h = f2bf_rne(a);
    l = f2bf_rne(a - bf2f(h));
}
__device__ __forceinline__ void make_afrag(const float* av, s8v& ah, s8v& al) {
    #pragma unroll
    for (int j = 0; j < 8; j++) {
        unsigned short h, l; split2(av[j], h, l);
        ah[j] = (short)h; al[j] = (short)l;
    }
}

__device__ __forceinline__ void stageW(const void* W, size_t offW, int KS, int f,
                                       unsigned short* sBhi, unsigned short* sBlo) {
    for (int idx = threadIdx.x; idx < KS * 2048; idx += 256) {
        int jj = idx & 7, ln = (idx >> 3) & 63, nt = (idx >> 9) & 3, ks = idx >> 11;
        int k = ks * 32 + (ln >> 4) * 8 + jj;
        int n = nt * 16 + (ln & 15);
        float w = ldx(W, offW + (size_t)k * 64 + n, f);
        unsigned short h_, l_; split2(w, h_, l_);
        sBhi[idx] = h_; sBlo[idx] = l_;
    }
}

__device__ __forceinline__ void mfma3(const unsigned short* sBhi, const unsigned short* sBlo,
                                      int ks, int lane, const s8v& ah, const s8v& al,
                                      f4v acc[4]) {
    #pragma unroll
    for (int nt = 0; nt < 4; nt++) {
        s8v bh = *(const s8v*)&sBhi[(ks * 4 + nt) * 512 + lane * 8];
        s8v bl = *(const s8v*)&sBlo[(ks * 4 + nt) * 512 + lane * 8];
        acc[nt] = __builtin_amdgcn_mfma_f32_16x16x32_bf16(ah, bh, acc[nt], 0, 0, 0);
        acc[nt] = __builtin_amdgcn_mfma_f32_16x16x32_bf16(al, bh, acc[nt], 0, 0, 0);
        acc[nt] = __builtin_amdgcn_mfma_f32_16x16x32_bf16(ah, bl, acc[nt], 0, 0, 0);
    }
}

__device__ __forceinline__ void ldrow8(const void* A, int fa, size_t row, int ks,
                                       int quad, float av[8]) {
    if (fa) {
        const float* p = (const float*)A + row * 64 + ks * 32 + quad * 8;
        float4 x0 = ((const float4*)p)[0], x1 = ((const float4*)p)[1];
        av[0] = x0.x; av[1] = x0.y; av[2] = x0.z; av[3] = x0.w;
        av[4] = x1.x; av[5] = x1.y; av[6] = x1.z; av[7] = x1.w;
    } else {
        const bf16* p = (const bf16*)A + row * 64 + ks * 32 + quad * 8;
        #pragma unroll
        for (int j = 0; j < 8; j++) av[j] = __bfloat162float(p[j]);
    }
}

// ---------------------------------------------------------------- diag helpers
__global__ void k_probe(const void* __restrict__ rbf, int* __restrict__ flag) {
    if (threadIdx.x == 0 && blockIdx.x == 0) {
        const float* p = (const float*)rbf;
        int good = 0;
        for (int i = 0; i < 256; i++) {
            float v = fabsf(p[i]);
            if (v > 1e-4f && v < 100.0f) good++;
        }
        *flag = (good > 192) ? 1 : 0;
    }
}
__global__ void k_fill(void* __restrict__ out, const int* __restrict__ flag,
                       float val, int n) {
    int i = blockIdx.x * blockDim.x + threadIdx.x;
    if (i < n) {
        if (*flag) ((float*)out)[i] = val;
        else       ((bf16*)out)[i] = __float2bfloat16(val);
    }
}

// ---------------------------------------------------------------- setup
__global__ void k_setup(const void* __restrict__ rbf, int* __restrict__ flag,
                        int* __restrict__ cur) {
    int i = blockIdx.x * blockDim.x + threadIdx.x;
    int stride = gridDim.x * blockDim.x;
    for (; i < 2 * N_NODES; i += stride) cur[i] = 0;
    if (blockIdx.x == 0 && threadIdx.x == 0) {
        const float* p = (const float*)rbf;
        int good = 0;
        for (int q = 0; q < 256; q++) {
            float v = fabsf(p[q]);
            if (v > 1e-4f && v < 100.0f) good++;
        }
        *flag = (good > 192) ? 1 : 0;
    }
}

__global__ void k_hist2(const int* __restrict__ j_idx, const int* __restrict__ edge_index,
                        int* __restrict__ cur_t, int* __restrict__ cur_e) {
    const int TB = (N_TRI + 255) / 256;
    if ((int)blockIdx.x < TB) {
        int i = blockIdx.x * 256 + threadIdx.x;
        if (i < N_TRI) {
            unsigned j = (unsigned)j_idx[i];
            if (j < N_NODES) atomicAdd(&cur_t[j], 1);
        }
    } else {
        int i = (blockIdx.x - TB) * 256 + threadIdx.x;
        if (i < N_EDGES) {
            unsigned d = (unsigned)edge_index[N_EDGES + i];
            if (d < N_NODES) atomicAdd(&cur_e[d], 1);
        }
    }
}

__global__ __launch_bounds__(256) void k_scan2(int* __restrict__ a, int* __restrict__ b) {
    int* cnt = (blockIdx.x == 0) ? a : b;
    __shared__ int part[256];
    int tid = threadIdx.x;
    const int PER = (N_NODES + 255) / 256;
    int base = tid * PER;
    int s = 0;
    for (int i = 0; i < PER; i++) {
        int idx = base + i;
        if (idx < N_NODES) s += cnt[idx];
    }
    part[tid] = s;
    __syncthreads();
    for (int d = 1; d < 256; d <<= 1) {
        int v = (tid >= d) ? part[tid - d] : 0;
        __syncthreads();
        part[tid] += v;
        __syncthreads();
    }
    int run = (tid > 0) ? part[tid - 1] : 0;
    for (int i = 0; i < PER; i++) {
        int idx = base + i;
        if (idx < N_NODES) {
            int v = cnt[idx];
            cnt[idx] = run;
            run += v;
        }
    }
}

__global__ void k_scatter2(const int* __restrict__ j_idx, const int* __restrict__ k_idx,
                           const int* __restrict__ edge_index,
                           int* __restrict__ cur_t, int* __restrict__ cur_e,
                           int* __restrict__ tri_o, int* __restrict__ k_srt,
                           int* __restrict__ src_s) {
    const int TB = (N_TRI + 255) / 256;
    if ((int)blockIdx.x < TB) {
        int i = blockIdx.x * 256 + threadIdx.x;
        if (i < N_TRI) {
            unsigned j = (unsigned)j_idx[i];
            if (j < N_NODES) {
                int pos = atomicAdd(&cur_t[j], 1);
                if ((unsigned)pos < (unsigned)N_TRI) {
                    unsigned k = (unsigned)k_idx[i]; if (k >= N_NODES) k = 0;
                    tri_o[pos] = i;
                    k_srt[pos] = (int)k;
                }
            }
        }
    } else {
        int e = (blockIdx.x - TB) * 256 + threadIdx.x;
        if (e < N_EDGES) {
            unsigned d = (unsigned)edge_index[N_EDGES + e];
            if (d < N_NODES) {
                int pos = atomicAdd(&cur_e[d], 1);
                if ((unsigned)pos < (unsigned)N_EDGES) {
                    unsigned s = (unsigned)edge_index[e]; if (s >= N_NODES) s = 0;
                    src_s[pos] = (int)s;
                }
            }
        }
    }
}

// ---------------------------------------------------------------- lin2out: Hh and Hs in one pass
__global__ __launch_bounds__(256) void k_lin2out(
    const void* __restrict__ A1, int a1ws,
    const void* __restrict__ W1, size_t offW1, const void* __restrict__ b1,
    const void* __restrict__ W2, size_t offW2, const void* __restrict__ b2,
    size_t offB, const int* __restrict__ flag,
    float* __restrict__ X, float* __restrict__ Y) {
    __shared__ unsigned short h1[2 * 2048], l1[2 * 2048];
    __shared__ unsigned short h2[2 * 2048], l2[2 * 2048];
    __shared__ float sB1[64], sB2[64];
    int f = *flag;
    int fa = a1ws ? 1 : f;
    stageW(W1, offW1, 2, f, h1, l1);
    stageW(W2, offW2, 2, f, h2, l2);
    if (threadIdx.x < 64) {
        sB1[threadIdx.x] = ldx(b1, offB + threadIdx.x, f);
        sB2[threadIdx.x] = ldx(b2, offB + threadIdx.x, f);
    }
    __syncthreads();
    int lane = threadIdx.x & 63;
    int quad = lane >> 4;
    int m = lane & 15;
    int tile = blockIdx.x * 4 + (threadIdx.x >> 6);
    size_t row = (size_t)tile * 16 + m;
    f4v accH[4], accS[4];
    #pragma unroll
    for (int nt = 0; nt < 4; nt++) {
        float bh = sB1[nt * 16 + m], bs = sB2[nt * 16 + m];
        accH[nt] = (f4v){bh, bh, bh, bh};
        accS[nt] = (f4v){bs, bs, bs, bs};
    }
    float av[8]; s8v ah, al;
    #pragma unroll
    for (int ks = 0; ks < 2; ks++) {
        ldrow8(A1, fa, row, ks, quad, av);
        make_afrag(av, ah, al);
        mfma3(h1, l1, ks, lane, ah, al, accH);
        mfma3(h2, l2, ks, lane, ah, al, accS);
    }
    #pragma unroll
    for (int r = 0; r < 4; r++) {
        size_t rr = (size_t)(tile * 16 + quad * 4 + r) * 64 + m;
        #pragma unroll
        for (int nt = 0; nt < 4; nt++) {
            NTS(&X[rr + nt * 16], accH[nt][r]);
            NTS(&Y[rr + nt * 16], accS[nt][r]);
        }
    }
}

// ---------------------------------------------------------------- generic 64x64 linear (for Ad)
__global__ __launch_bounds__(256) void k_lin1(
    const float* __restrict__ A, const void* __restrict__ W, size_t offW,
    const int* __restrict__ flag, float* __restrict__ out) {
    __shared__ unsigned short wh[2 * 2048], wl[2 * 2048];
    int f = *flag;
    stageW(W, offW, 2, f, wh, wl);
    __syncthreads();
    int lane = threadIdx.x & 63;
    int quad = lane >> 4;
    int m = lane & 15;
    int tile = blockIdx.x * 4 + (threadIdx.x >> 6);
    size_t row = (size_t)tile * 16 + m;
    f4v acc[4];
    #pragma unroll
    for (int nt = 0; nt < 4; nt++) acc[nt] = (f4v){0.f, 0.f, 0.f, 0.f};
    float av[8]; s8v ah, al;
    #pragma unroll
    for (int ks = 0; ks < 2; ks++) {
        ldrow8(A, 1, row, ks, quad, av);
        make_afrag(av, ah, al);
        mfma3(wh, wl, ks, lane, ah, al, acc);
    }
    #pragma unroll
    for (int r = 0; r < 4; r++) {
        size_t rr = (size_t)(tile * 16 + quad * 4 + r) * 64 + m;
        #pragma unroll
        for (int nt = 0; nt < 4; nt++)
            NTS(&out[rr + nt * 16], acc[nt][r]);
    }
}

// ---------------------------------------------------------------- tri segment sum
__global__ __launch_bounds__(256) void k_tri_seg(
    const int* __restrict__ ends, const int* __restrict__ tri_o,
    const int* __restrict__ k_srt, const float* __restrict__ Hh,
    const void* __restrict__ rbf, const void* __restrict__ cbf,
    const void* __restrict__ W1, size_t offW,
    const int* __restrict__ flag, float* __restrict__ agg_e) {
    int f = *flag;
    int c = threadIdx.x & 63;
    float wr[6], wc[6];
    #pragma unroll
    for (int q = 0; q < 6; q++) {
        wr[q] = ldx(W1, offW + (size_t)(64 + q) * 64 + c, f);
        wc[q] = ldx(W1, offW + (size_t)(70 + q) * 64 + c, f);
    }
    int j = blockIdx.x * 4 + (threadIdx.x >> 6);
    int p0 = (j == 0) ? 0 : ends[j - 1];
    int p1 = ends[j];
    if (p0 < 0) p0 = 0; if (p0 > N_TRI) p0 = N_TRI;
    if (p1 < p0) p1 = p0; if (p1 > N_TRI) p1 = N_TRI;
    float rb = 0.f;
    #pragma unroll
    for (int q = 0; q < 6; q++)
        rb += ldx(rbf, (size_t)j * 6 + q, f) * wr[q];
    float s = 0.f;
    for (int p = p0; p < p1; p += 4) {
        int tq[4], kq[4];
        float hv[4], cb[4][6];
        #pragma unroll
        for (int i = 0; i < 4; i++) {
            int ok = (p + i < p1);
            int t = ok ? tri_o[p + i] : -1;
            if ((unsigned)t >= N_TRI) t = -1;
            tq[i] = t;
            int k = ok ? k_srt[p + i] : 0;
            if ((unsigned)k >= N_NODES) k = 0;
            kq[i] = k;
        }
        #pragma unroll
        for (int i = 0; i < 4; i++)
            hv[i] = Hh[(size_t)kq[i] * 64 + c];
        #pragma unroll
        for (int i = 0; i < 4; i++) {
            if (tq[i] >= 0) {
                if (f) {
                    const float2* cp = (const float2*)((const float*)cbf + (size_t)tq[i] * 6);
                    float2 c0 = cp[0], c1 = cp[1], c2 = cp[2];
                    cb[i][0] = c0.x; cb[i][1] = c0.y; cb[i][2] = c1.x;
                    cb[i][3] = c1.y; cb[i][4] = c2.x; cb[i][5] = c2.y;
                } else {
                    #pragma unroll
                    for (int q = 0; q < 6; q++)
                        cb[i][q] = ldx(cbf, (size_t)tq[i] * 6 + q, 0);
                }
            }
        }
        #pragma unroll
        for (int i = 0; i < 4; i++) {
            if (tq[i] < 0) continue;
            float v = hv[i] + rb;
            #pragma unroll
            for (int q = 0; q < 6; q++)
                v += cb[i][q] * wc[q];
            s += fmaxf(v, 0.f);
        }
    }
    NTS(&agg_e[(size_t)j * 64 + c], s);
}

// ---------------------------------------------------------------- edge segment sum (Ad precomputed)
__global__ __launch_bounds__(256) void k_edge_s(
    const int* __restrict__ ends, const int* __restrict__ src_s,
    const float* __restrict__ Hs, const float* __restrict__ Ad,
    float* __restrict__ aggr) {
    int c = threadIdx.x & 63;
    int d = blockIdx.x * 4 + (threadIdx.x >> 6);
    int p0 = (d == 0) ? 0 : ends[d - 1];
    int p1 = ends[d];
    if (p0 < 0) p0 = 0; if (p0 > N_EDGES) p0 = N_EDGES;
    if (p1 < p0) p1 = p0; if (p1 > N_EDGES) p1 = N_EDGES;
    float ad = Ad[(size_t)d * 64 + c];
    float s = 0.f;
    for (int p = p0; p < p1; p += 8) {
        int ss[8];
        float hv[8];
        #pragma unroll
        for (int i = 0; i < 8; i++) {
            int sv = (p + i < p1) ? src_s[p + i] : 0;
            if ((unsigned)sv >= N_NODES) sv = 0;
            ss[i] = sv;
        }
        #pragma unroll
        for (int i = 0; i < 8; i++)
            hv[i] = Hs[(size_t)ss[i] * 64 + c];
        #pragma unroll
        for (int i = 0; i < 8; i++)
            if (p + i < p1) s += fmaxf(hv[i] + ad, 0.f);
    }
    NTS(&aggr[(size_t)d * 64 + c], s);
}

// ---------------------------------------------------------------- fused node MLP
__global__ __launch_bounds__(256) void k_node_f(
    const void* __restrict__ A1, int a1ws, const float* __restrict__ aggr,
    const void* __restrict__ Wn1, const void* __restrict__ bn1,
    const void* __restrict__ Wn2, const void* __restrict__ bn2,
    size_t offW1, size_t offB, size_t offW2,
    const int* __restrict__ flag, float* __restrict__ hout) {
    __shared__ unsigned short s1h[4 * 2048], s1l[4 * 2048];
    __shared__ unsigned short s2h[2 * 2048], s2l[2 * 2048];
    __shared__ float sB1[64], sB2[64];
    __shared__ float zbuf[4][16 * 68];
    int f = *flag;
    int fa = a1ws ? 1 : f;
    stageW(Wn1, offW1, 4, f, s1h, s1l);
    stageW(Wn2, offW2, 2, f, s2h, s2l);
    if (threadIdx.x < 64) {
        sB1[threadIdx.x] = ldx(bn1, offB + threadIdx.x, f);
        sB2[threadIdx.x] = ldx(bn2, offB + threadIdx.x, f);
    }
    __syncthreads();
    int lane = threadIdx.x & 63;
    int quad = lane >> 4;
    int m = lane & 15;
    int w = threadIdx.x >> 6;
    int tile = blockIdx.x * 4 + w;
    size_t row = (size_t)tile * 16 + m;
    f4v acc[4];
    #pragma unroll
    for (int nt = 0; nt < 4; nt++) {
        float b = sB1[nt * 16 + m];
        acc[nt] = (f4v){b, b, b, b};
    }
    float av[8]; s8v ah, al;
    #pragma unroll
    for (int ks = 0; ks < 2; ks++) {
        ldrow8(A1, fa, row, ks, quad, av);
        make_afrag(av, ah, al);
        mfma3(s1h, s1l, ks, lane, ah, al, acc);
    }
    #pragma unroll
    for (int ks = 0; ks < 2; ks++) {
        ldrow8(aggr, 1, row, ks, quad, av);
        make_afrag(av, ah, al);
        mfma3(s1h, s1l, 2 + ks, lane, ah, al, acc);
    }
    #pragma unroll
    for (int r = 0; r < 4; r++)
        #pragma unroll
        for (int nt = 0; nt < 4; nt++)
            zbuf[w][(quad * 4 + r) * 68 + nt * 16 + m] = fmaxf(acc[nt][r], 0.f);
    f4v acc2[4];
    #pragma unroll
    for (int nt = 0; nt < 4; nt++) {
        float b = sB2[nt * 16 + m];
        acc2[nt] = (f4v){b, b, b, b};
    }
    #pragma unroll
    for (int ks = 0; ks < 2; ks++) {
        #pragma unroll
        for (int jx = 0; jx < 8; jx++)
            av[jx] = zbuf[w][m * 68 + ks * 32 + quad * 8 + jx];
        make_afrag(av, ah, al);
        mfma3(s2h, s2l, ks, lane, ah, al, acc2);
    }
    #pragma unroll
    for (int r = 0; r < 4; r++) {
        size_t rr = (size_t)(tile * 16 + quad * 4 + r) * 64 + m;
        #pragma unroll
        for (int nt = 0; nt < 4; nt++)
            NTS(&hout[rr + nt * 16], acc2[nt][r]);
    }
}

// ---------------------------------------------------------------- pool + head
__global__ __launch_bounds__(256) void k_poolhead(
    const float* __restrict__ h, const int* __restrict__ batch,
    const void* __restrict__ Wo1, const void* __restrict__ bo1,
    const void* __restrict__ Wo2, const void* __restrict__ bo2,
    const int* __restrict__ flag, void* __restrict__ out) {
    __shared__ float red[4][64];
    int b = blockIdx.x;
    int lo = 0, hi = N_NODES;
    while (lo < hi) { int mid = (lo + hi) >> 1; if (batch[mid] < b) lo = mid + 1; else hi = mid; }
    int start = lo;
    hi = N_NODES;
    while (lo < hi) { int mid = (lo + hi) >> 1; if (batch[mid] < b + 1) lo = mid + 1; else hi = mid; }
    int end = lo;
    int lane = threadIdx.x & 63;
    int w = threadIdx.x >> 6;
    float s = 0.f;
    for (int n = start + w; n < end; n += 4)
        s += h[(size_t)n * 64 + lane];
    red[w][lane] = s;
    __syncthreads();
    if (w == 0) {
        int f = *flag;
        float tot = red[0][lane] + red[1][lane] + red[2][lane] + red[3][lane];
        float c = (float)(end - start);
        float p = fmaxf(tot / fmaxf(c, 1.0f), 0.f);
        float acc = ldx(bo1, lane, f);
        #pragma unroll
        for (int kk = 0; kk < 64; kk++)
            acc += __shfl(p, kk) * ldx(Wo1, kk * 64 + lane, f);
        float t1 = fmaxf(acc, 0.f);
        float acc2 = (lane < OUT_DIM) ? ldx(bo2, lane, f) : 0.f;
        #pragma unroll
        for (int kk = 0; kk < 64; kk++) {
            float wv = (lane < OUT_DIM) ? ldx(Wo2, kk * OUT_DIM + lane, f) : 0.f;
            acc2 += __shfl(t1, kk) * wv;
        }
        if (lane < OUT_DIM) {
            if (f) ((float*)out)[b * OUT_DIM + lane] = acc2;
            else   ((bf16*)out)[b * OUT_DIM + lane] = __float2bfloat16(acc2);
        }
    }
}

extern "C" void kernel_launch(void* const* d_in, const int* in_sizes, int n_in,
                              void* d_out, int out_size, void* d_ws, size_t ws_size,
                              hipStream_t stream) {
    const int expect[19] = {
        N_NODES * 64, N_EDGES * 6, N_TRI * 6,
        L_LAYERS * 76 * 64, L_LAYERS * 64,
        L_LAYERS * 128 * 64, L_LAYERS * 64,
        L_LAYERS * 128 * 64, L_LAYERS * 64,
        L_LAYERS * 64 * 64, L_LAYERS * 64,
        64 * 64, 64, 64 * OUT_DIM, OUT_DIM,
        2 * N_EDGES, N_TRI, N_TRI, N_NODES
    };

    char* ws = (char*)d_ws;
    float* hA     = (float*)(ws + 0);            // 4,096,000
    float* agg_e  = (float*)(ws + 4096000);      // 4,096,000
    float* aggr   = (float*)(ws + 8192000);      // 4,096,000
    float* X      = (float*)(ws + 12288000);     // 4,096,000 (Hh, then Ad)
    float* Y      = (float*)(ws + 16384000);     // 4,096,000 (Hs)
    int*   flag   = (int*)(ws + 20480000);       // 256
    int*   cur_t  = (int*)(ws + 20480256);       // 64,000
    int*   cur_e  = (int*)(ws + 20544256);       // 64,000
    int*   tri_o  = (int*)(ws + 20608256);       // 2,560,000
    int*   k_srt  = (int*)(ws + 23168256);       // 2,560,000
    int*   src_s  = (int*)(ws + 25728256);       // 1,024,000
    float* hB     = (float*)(ws + 26752256);     // 4,096,000
    const size_t FULL_NEED = 30848256u;

    const int out_n = N_B * OUT_DIM;

    int perm[19];
    bool used[64];
    for (int i = 0; i < 64; i++) used[i] = false;
    int fail_slot = -1;
    for (int i = 0; i < 19; i++) {
        perm[i] = -1;
        for (int jj = 0; jj < n_in && jj < 64; jj++) {
            if (!used[jj] && in_sizes[jj] == expect[i]) { used[jj] = true; perm[i] = jj; break; }
        }
        if (perm[i] < 0 && fail_slot < 0) fail_slot = i;
    }

    if (n_in < 19 || fail_slot >= 0 || ws_size < FULL_NEED) {
        float code = (ws_size < FULL_NEED) ? 40000.0f
                   : (n_in < 19)           ? 50000.0f
                   : 20000.0f + 1000.0f * (float)fail_slot;
        k_probe<<<1, 64, 0, stream>>>(d_in[0], (int*)d_ws);
        k_fill<<<(out_n + 255) / 256, 256, 0, stream>>>(d_out, (int*)d_ws, code, out_n);
        return;
    }

    const void* x    = d_in[perm[0]];
    const void* rbf  = d_in[perm[1]];
    const void* cbf  = d_in[perm[2]];
    const void* W1   = d_in[perm[3]];
    const void* b1   = d_in[perm[4]];
    const void* W2   = d_in[perm[5]];
    const void* b2   = d_in[perm[6]];
    const void* Wn1  = d_in[perm[7]];
    const void* bn1  = d_in[perm[8]];
    const void* Wn2  = d_in[perm[9]];
    const void* bn2  = d_in[perm[10]];
    const void* Wo1  = d_in[perm[11]];
    const void* bo1  = d_in[perm[12]];
    const void* Wo2  = d_in[perm[13]];
    const void* bo2  = d_in[perm[14]];
    const int* edge_index = (const int*)d_in[perm[15]];
    const int* k_idx = (const int*)d_in[perm[16]];
    const int* j_idx = (const int*)d_in[perm[17]];
    const int* batch = (const int*)d_in[perm[18]];

    const int TB = (N_TRI + 255) / 256;
    const int EB = (N_EDGES + 255) / 256;

    k_setup<<<64, 256, 0, stream>>>(rbf, flag, cur_t);
    k_hist2<<<TB + EB, 256, 0, stream>>>(j_idx, edge_index, cur_t, cur_e);
    k_scan2<<<2, 256, 0, stream>>>(cur_t, cur_e);
    k_scatter2<<<TB + EB, 256, 0, stream>>>(j_idx, k_idx, edge_index,
                                            cur_t, cur_e, tri_o, k_srt, src_s);

    // ping-pong h: l0: x->hA, l1: hA->hB, l2: hB->hA; poolhead reads hA
    const void* hc = x;
    int hws = 0;
    float* hout = hA;
    for (int l = 0; l < L_LAYERS; l++) {
        size_t offW1l = (size_t)l * 76 * 64;
        size_t offW2l = (size_t)l * 128 * 64;
        size_t offWn2 = (size_t)l * 64 * 64;
        size_t offB   = (size_t)l * 64;
        // Hh -> X, Hs -> Y (one pass over h)
        k_lin2out<<<250, 256, 0, stream>>>(hc, hws, W1, offW1l, b1,
                                           W2, offW2l, b2, offB, flag, X, Y);
        // agg_e = segsum_j relu(Hh[k] + rbf[j]@W1r + cbf[t]@W1c)
        k_tri_seg<<<4000, 256, 0, stream>>>(cur_t, tri_o, k_srt, X, rbf, cbf,
                                            W1, offW1l, flag, agg_e);
        // Ad = agg_e @ W2a  (MFMA; X is dead after tri_seg -> reuse as Ad)
        k_lin1<<<250, 256, 0, stream>>>(agg_e, W2, offW2l + 64 * 64, flag, X);
        // aggr = segsum_d relu(Hs[src] + Ad[d])
        k_edge_s<<<4000, 256, 0, stream>>>(cur_e, src_s, Y, X, aggr);
        // h' = relu([h|aggr]@Wn1+bn1)@Wn2+bn2
        k_node_f<<<250, 256, 0, stream>>>(hc, hws, aggr, Wn1, bn1, Wn2, bn2,
                                          offW2l, offB, offWn2, flag, hout);
        hc = hout; hws = 1;
        hout = (hout == hA) ? hB : hA;
    }
    k_poolhead<<<N_B, 256, 0, stream>>>(hA, batch, Wo1, bo1, Wo2, bo2, flag, d_out);
}